// Round 1
// baseline (25.412 us; speedup 1.0000x reference)
//
#include <hip/hip_runtime.h>

// ROI pooling (bilinear resize of each ROI to 7x7), matching the JAX reference.
// image: (1, 200, 200, 512) f32, NHWC (C innermost)
// rois:  (1, 300, 4) f32 = (x, y, w, h) integer-valued
// out:   (1, 300, 7, 7, 512) f32

#define POOL   7
#define N_ROI  300
#define IMG_H  200
#define IMG_W  200
#define CH     512
#define CH4    (CH / 4)   // 128 float4 per pixel

__global__ __launch_bounds__(CH4) void roi_pool_kernel(
        const float* __restrict__ image,
        const float* __restrict__ rois,
        float* __restrict__ out) {
    const int b = blockIdx.x;           // b = r*49 + p*7 + q
    const int q = b % POOL;
    const int p = (b / POOL) % POOL;
    const int r = b / (POOL * POOL);

    // ROI params (x, y, w, h) — integer-valued floats.
    const float4 rv = ((const float4*)rois)[r];
    const int x = (int)rv.x;
    const int y = (int)rv.y;
    const int w = (int)rv.z;
    const int h = (int)rv.w;

    // Legacy resize: src = out_coord * (in/out), floor / floor+1 clamped.
    // Replicate reference float32 arithmetic: arange * (h/7.0f).
    const float sy = (float)p * ((float)h / 7.0f);
    int y0 = (int)floorf(sy);
    int y1 = min(y0 + 1, h - 1);
    const float fy = sy - (float)y0;

    const float sx = (float)q * ((float)w / 7.0f);
    int x0 = (int)floorf(sx);
    int x1 = min(x0 + 1, w - 1);
    const float fx = sx - (float)x0;

    const long long row0 = (long long)(y + y0) * IMG_W;
    const long long row1 = (long long)(y + y1) * IMG_W;
    const long long c00 = (row0 + (x + x0)) * CH4;
    const long long c01 = (row0 + (x + x1)) * CH4;
    const long long c10 = (row1 + (x + x0)) * CH4;
    const long long c11 = (row1 + (x + x1)) * CH4;

    const float w00 = (1.0f - fy) * (1.0f - fx);
    const float w01 = (1.0f - fy) * fx;
    const float w10 = fy * (1.0f - fx);
    const float w11 = fy * fx;

    const float4* __restrict__ img4 = (const float4*)image;
    float4* __restrict__ out4 = (float4*)out;

    const int c = threadIdx.x;          // 0..127
    const float4 v00 = img4[c00 + c];
    const float4 v01 = img4[c01 + c];
    const float4 v10 = img4[c10 + c];
    const float4 v11 = img4[c11 + c];

    float4 o;
    o.x = v00.x * w00 + v01.x * w01 + v10.x * w10 + v11.x * w11;
    o.y = v00.y * w00 + v01.y * w01 + v10.y * w10 + v11.y * w11;
    o.z = v00.z * w00 + v01.z * w01 + v10.z * w10 + v11.z * w11;
    o.w = v00.w * w00 + v01.w * w01 + v10.w * w10 + v11.w * w11;

    out4[(long long)b * CH4 + c] = o;
}

extern "C" void kernel_launch(void* const* d_in, const int* in_sizes, int n_in,
                              void* d_out, int out_size, void* d_ws, size_t ws_size,
                              hipStream_t stream) {
    const float* image = (const float*)d_in[0];
    const float* rois  = (const float*)d_in[1];
    float* out = (float*)d_out;

    const int nblocks = N_ROI * POOL * POOL;   // 14700
    roi_pool_kernel<<<nblocks, CH4, 0, stream>>>(image, rois, out);
}

// Round 3
// 21.851 us; speedup vs baseline: 1.1629x; 1.1629x over previous
//
#include <hip/hip_runtime.h>

// ROI pooling (bilinear resize of each ROI to 7x7), matching the JAX reference.
// image: (1, 200, 200, 512) f32 NHWC; rois: (1, 300, 4) f32 (x,y,w,h); out: (1,300,7,7,512) f32.
//
// R3: same as R2 but with native ext_vector float4 so nontemporal builtins compile.
// 2 cells/block (8 loads in flight), bijective XCD swizzle for same-ROI L2 reuse,
// nontemporal output stores (output is write-once, spare the caches for the image).

#define POOL   7
#define N_ROI  300
#define IMG_W  200
#define CH4    128           // 512 channels / 4 = float4 groups per pixel
#define NCELL  (N_ROI * POOL * POOL)   // 14700
#define NBLK   (NCELL / 2)             // 7350
#define NXCD   8

typedef float f4 __attribute__((ext_vector_type(4)));

struct Cell {
    int c00, c01, c10, c11;   // float4 base indices of the 4 corner pixels
    float w00, w01, w10, w11;
};

__device__ inline Cell decode_cell(const f4* __restrict__ rois4, int b) {
    const int q = b % POOL;
    const int t = b / POOL;
    const int p = t % POOL;
    const int r = t / POOL;

    const f4 rv = rois4[r];
    const int x = (int)rv.x;
    const int y = (int)rv.y;
    const int w = (int)rv.z;
    const int h = (int)rv.w;

    // Legacy resize arithmetic, replicated in f32 exactly as the reference.
    const float sy = (float)p * ((float)h / 7.0f);
    const int y0 = (int)floorf(sy);
    const int y1 = min(y0 + 1, h - 1);
    const float fy = sy - (float)y0;

    const float sx = (float)q * ((float)w / 7.0f);
    const int x0 = (int)floorf(sx);
    const int x1 = min(x0 + 1, w - 1);
    const float fx = sx - (float)x0;

    const int row0 = (y + y0) * IMG_W;
    const int row1 = (y + y1) * IMG_W;

    Cell cl;
    cl.c00 = (row0 + x + x0) * CH4;
    cl.c01 = (row0 + x + x1) * CH4;
    cl.c10 = (row1 + x + x0) * CH4;
    cl.c11 = (row1 + x + x1) * CH4;
    cl.w00 = (1.0f - fy) * (1.0f - fx);
    cl.w01 = (1.0f - fy) * fx;
    cl.w10 = fy * (1.0f - fx);
    cl.w11 = fy * fx;
    return cl;
}

__device__ inline f4 blend(f4 a, f4 b, f4 c, f4 d,
                           float wa, float wb, float wc, float wd) {
    return a * wa + b * wb + c * wc + d * wd;
}

__global__ __launch_bounds__(CH4) void roi_pool_kernel(
        const float* __restrict__ image,
        const float* __restrict__ rois,
        float* __restrict__ out) {
    // Bijective XCD swizzle: contiguous chunks of block-space per XCD so that
    // the ~25 blocks of one ROI (overlapping pixel reads) share one L2.
    const int bid = blockIdx.x;
    const int qc = NBLK / NXCD;        // 918
    const int rm = NBLK % NXCD;        // 6
    const int xcd = bid % NXCD;
    const int idx = bid / NXCD;
    const int blk = (xcd < rm ? xcd * (qc + 1)
                              : rm * (qc + 1) + (xcd - rm) * qc) + idx;

    const int c = threadIdx.x;          // 0..127 (float4 channel group)
    const f4* __restrict__ img4  = (const f4*)image;
    const f4* __restrict__ rois4 = (const f4*)rois;
    f4* __restrict__ out4 = (f4*)out;

    const int b0 = blk * 2;
    const int b1 = b0 + 1;

    const Cell cA = decode_cell(rois4, b0);
    const Cell cB = decode_cell(rois4, b1);

    // Issue all 8 loads before any blend — 8 outstanding VMEM ops per thread.
    const f4 a00 = img4[cA.c00 + c];
    const f4 a01 = img4[cA.c01 + c];
    const f4 a10 = img4[cA.c10 + c];
    const f4 a11 = img4[cA.c11 + c];
    const f4 b00 = img4[cB.c00 + c];
    const f4 b01 = img4[cB.c01 + c];
    const f4 b10 = img4[cB.c10 + c];
    const f4 b11 = img4[cB.c11 + c];

    const f4 oA = blend(a00, a01, a10, a11, cA.w00, cA.w01, cA.w10, cA.w11);
    const f4 oB = blend(b00, b01, b10, b11, cB.w00, cB.w01, cB.w10, cB.w11);

    // Output is write-once/never-read: nontemporal to spare L2/L3 for the image.
    __builtin_nontemporal_store(oA, &out4[b0 * CH4 + c]);
    __builtin_nontemporal_store(oB, &out4[b1 * CH4 + c]);
}

extern "C" void kernel_launch(void* const* d_in, const int* in_sizes, int n_in,
                              void* d_out, int out_size, void* d_ws, size_t ws_size,
                              hipStream_t stream) {
    const float* image = (const float*)d_in[0];
    const float* rois  = (const float*)d_in[1];
    float* out = (float*)d_out;

    roi_pool_kernel<<<NBLK, CH4, 0, stream>>>(image, rois, out);
}